// Round 2
// 224.046 us; speedup vs baseline: 1.0068x; 1.0068x over previous
//
#include <hip/hip_runtime.h>
#include <math.h>

#define NPAR 8
#define DIM  16
#define HID  128
#define BATCH 4096
#define VSTRF 132              // stride (floats) per 128-vector in LDS
#define NVEC 9                 // base + 8 tangent directions

typedef float v2f __attribute__((ext_vector_type(2)));
typedef float v4f __attribute__((ext_vector_type(4)));

// Force the packed-FP32 pipe: d = a*b + d (per 2-lane component).
#define PKFMA(d, a, b) asm("v_pk_fma_f32 %0, %1, %2, %0" : "+v"(d) : "v"(a), "v"(b))

// Packed f32 weights (exact copies of f32 inputs) in static device memory.
// Layout (float offsets): PF2@0 PB2@16384 PF3@32768 PB3@49152 PF4@65536 PB4@81920 PB1@98304
// pos(jo,kr) = (((kr>>6)*16 + ((kr&63)>>2))*4 + (jo>>5))*128 + (jo&31)*4 + (kr&3)
__device__ float g_wsf[6*HID*HID + HID*DIM];

__device__ __forceinline__ float sigf(float z){ return 1.0f/(1.0f+__expf(-z)); }
__device__ __forceinline__ float spf(float z){ return fmaxf(z,0.0f)+log1pf(__expf(-fabsf(z))); }

// Destination-indexed (coalesced-write) packer. Each thread writes one float4.
// Inverse of pos(): p -> (jo, kr0..kr0+3):
//   low=p&127: jo_low5=low>>2, kr_low2(low&3) spans 0..3 within a float4
//   B=p>>7: jo = (B&3)*32 + jo_low5 ; T=B>>2: kr0 = (T>>4)*64 + (T&15)*4
__global__ __launch_bounds__(256)
void pack_weights(const float* __restrict__ W1, const float* __restrict__ W2,
                  const float* __restrict__ W3, const float* __restrict__ W4) {
  int t = blockIdx.x*blockDim.x + threadIdx.x;   // 25088 threads total
  int p4 = t*4;
  float4 r;
  if (p4 < 6*HID*HID) {
    int ri = p4 >> 14;                            // 0..5: PF2 PB2 PF3 PB3 PF4 PB4
    const float* W = (ri < 2) ? W2 : ((ri < 4) ? W3 : W4);
    int p  = p4 & 16383;
    int low = p & 127;
    int B  = p >> 7;
    int jo = (B & 3)*32 + (low >> 2);
    int T  = B >> 2;
    int kr0 = (T >> 4)*64 + (T & 15)*4;
    if ((ri & 1) == 0) {
      // PF[p..p+3] = W[jo][kr0..kr0+3]  (contiguous row-major read)
      r = *((const float4*)(W + jo*HID + kr0));
    } else {
      // PB[p+c] = W[kr0+c][jo]
      r.x = W[(kr0+0)*HID + jo];
      r.y = W[(kr0+1)*HID + jo];
      r.z = W[(kr0+2)*HID + jo];
      r.w = W[(kr0+3)*HID + jo];
    }
  } else {
    // W1 region: idx = (k>>2)*64 + m2*4 + (k&3); float4 spans (k&3)=0..3
    int rr = p4 - 6*HID*HID;                      // 0..2047
    int k0 = (rr >> 6)*4;
    int m2 = (rr >> 2) & 15;
    r.x = W1[(k0+0)*DIM + m2];
    r.y = W1[(k0+1)*DIM + m2];
    r.z = W1[(k0+2)*DIM + m2];
    r.w = W1[(k0+3)*DIM + m2];
  }
  *((float4*)(g_wsf + p4)) = r;
}

// All-f32 split-K fused 9-vector GEMV using forced v_pk_fma_f32 over k-pairs.
// Lane (o,kh) covers k-half kh for outputs {o,o+32,o+64,o+96}; after the
// shfl_xor(32) reduction the lane keeps j_a = o+64*kh (zA), j_b = j_a+32 (zB).
__device__ __forceinline__ void gemv9f32(const float* __restrict__ Wbase,
    const float* __restrict__ bin, int o, int kh, float* zA, float* zB) {
  const v4f* Wq = (const v4f*)Wbase;
  const float* hb = bin + kh*64;
  v2f acc[4][NVEC];
#pragma unroll
  for (int jj=0;jj<4;++jj)
#pragma unroll
    for (int v=0;v<NVEC;++v) acc[jj][v] = (v2f){0.0f, 0.0f};
#pragma unroll 4
  for (int q=0;q<16;++q){
    int base = ((kh*16+q)*4)*32 + o;
    v4f w0 = Wq[base], w1 = Wq[base+32], w2 = Wq[base+64], w3 = Wq[base+96];
    v2f w0a=w0.xy, w0b=w0.zw;
    v2f w1a=w1.xy, w1b=w1.zw;
    v2f w2a=w2.xy, w2b=w2.zw;
    v2f w3a=w3.xy, w3b=w3.zw;
#pragma unroll
    for (int v=0;v<NVEC;++v){
      v4f h = *((const v4f*)(hb + v*VSTRF + 4*q));   // LDS broadcast
      v2f ha=h.xy, hc=h.zw;
      PKFMA(acc[0][v], w0a, ha); PKFMA(acc[0][v], w0b, hc);
      PKFMA(acc[1][v], w1a, ha); PKFMA(acc[1][v], w1b, hc);
      PKFMA(acc[2][v], w2a, ha); PKFMA(acc[2][v], w2b, hc);
      PKFMA(acc[3][v], w3a, ha); PKFMA(acc[3][v], w3b, hc);
    }
  }
#pragma unroll
  for (int v=0;v<NVEC;++v){
    float u0 = acc[0][v].x + acc[0][v].y;
    float u1 = acc[1][v].x + acc[1][v].y;
    float u2 = acc[2][v].x + acc[2][v].y;
    float u3 = acc[3][v].x + acc[3][v].y;
    u0 += __shfl_xor(u0,32);
    u1 += __shfl_xor(u1,32);
    u2 += __shfl_xor(u2,32);
    u3 += __shfl_xor(u3,32);
    zA[v] = kh ? u2 : u0;
    zB[v] = kh ? u3 : u1;
  }
}

__global__ __launch_bounds__(64)
__attribute__((amdgpu_waves_per_eu(2)))
void lnn_main(const float* __restrict__ x, const float* __restrict__ W1,
              const float* __restrict__ b1, const float* __restrict__ b2,
              const float* __restrict__ b3, const float* __restrict__ b4,
              const float* __restrict__ W5, float* __restrict__ out) {
  const int l  = threadIdx.x;
  const int o  = l & 31;
  const int kh = l >> 5;
  const int ja = o + 64*kh;
  const int jb = ja + 32;
  const int s  = blockIdx.x;           // one sample per wave

  __shared__ __align__(16) float buf[NVEC*VSTRF];  // base @0, tangents @(1+i)
  __shared__ float xs[16];

  if (l < DIM) xs[l] = x[s*DIM + l];
  __syncthreads();

  // ---- Phase 1: layer 1 (rows ja, jb) ----
  const float4* W1v = (const float4*)W1;
  float s1a, s1b;
  float w1af[8], w1bf[8];
  {
    float4 a0 = W1v[ja*4+0], a1 = W1v[ja*4+1], a2 = W1v[ja*4+2], a3 = W1v[ja*4+3];
    float4 c0 = W1v[jb*4+0], c1 = W1v[jb*4+1], c2 = W1v[jb*4+2], c3 = W1v[jb*4+3];
    float z1a = b1[ja], z1b = b1[jb];
    z1a = fmaf(a0.x, xs[0],  z1a); z1a = fmaf(a0.y, xs[1],  z1a);
    z1a = fmaf(a0.z, xs[2],  z1a); z1a = fmaf(a0.w, xs[3],  z1a);
    z1a = fmaf(a1.x, xs[4],  z1a); z1a = fmaf(a1.y, xs[5],  z1a);
    z1a = fmaf(a1.z, xs[6],  z1a); z1a = fmaf(a1.w, xs[7],  z1a);
    z1a = fmaf(a2.x, xs[8],  z1a); z1a = fmaf(a2.y, xs[9],  z1a);
    z1a = fmaf(a2.z, xs[10], z1a); z1a = fmaf(a2.w, xs[11], z1a);
    z1a = fmaf(a3.x, xs[12], z1a); z1a = fmaf(a3.y, xs[13], z1a);
    z1a = fmaf(a3.z, xs[14], z1a); z1a = fmaf(a3.w, xs[15], z1a);
    z1b = fmaf(c0.x, xs[0],  z1b); z1b = fmaf(c0.y, xs[1],  z1b);
    z1b = fmaf(c0.z, xs[2],  z1b); z1b = fmaf(c0.w, xs[3],  z1b);
    z1b = fmaf(c1.x, xs[4],  z1b); z1b = fmaf(c1.y, xs[5],  z1b);
    z1b = fmaf(c1.z, xs[6],  z1b); z1b = fmaf(c1.w, xs[7],  z1b);
    z1b = fmaf(c2.x, xs[8],  z1b); z1b = fmaf(c2.y, xs[9],  z1b);
    z1b = fmaf(c2.z, xs[10], z1b); z1b = fmaf(c2.w, xs[11], z1b);
    z1b = fmaf(c3.x, xs[12], z1b); z1b = fmaf(c3.y, xs[13], z1b);
    z1b = fmaf(c3.z, xs[14], z1b); z1b = fmaf(c3.w, xs[15], z1b);
    s1a = sigf(z1a); s1b = sigf(z1b);
    buf[ja] = spf(z1a); buf[jb] = spf(z1b);
    w1af[0]=a2.x; w1af[1]=a2.y; w1af[2]=a2.z; w1af[3]=a2.w;
    w1af[4]=a3.x; w1af[5]=a3.y; w1af[6]=a3.z; w1af[7]=a3.w;
    w1bf[0]=c2.x; w1bf[1]=c2.y; w1bf[2]=c2.z; w1bf[3]=c2.w;
    w1bf[4]=c3.x; w1bf[5]=c3.y; w1bf[6]=c3.z; w1bf[7]=c3.w;
#pragma unroll
    for (int i=0;i<8;++i){
      buf[(1+i)*VSTRF + ja] = s1a*w1af[i];     // t_h1
      buf[(1+i)*VSTRF + jb] = s1b*w1bf[i];
    }
  }
  __syncthreads();

  float zA[NVEC], zB[NVEC];

  // ---- Phase 2: layer 2 forward (PF2) ----
  gemv9f32(g_wsf + 0, buf, o, kh, zA, zB);
  float z2a = zA[0] + b2[ja], z2b = zB[0] + b2[jb];
  float t2a[8], t2b[8];
#pragma unroll
  for (int i=0;i<8;++i){ t2a[i]=zA[1+i]; t2b[i]=zB[1+i]; }
  float s2a = sigf(z2a), s2b = sigf(z2b);
  __syncthreads();
  buf[ja] = spf(z2a); buf[jb] = spf(z2b);
#pragma unroll
  for (int i=0;i<8;++i){
    buf[(1+i)*VSTRF + ja] = s2a*zA[1+i];
    buf[(1+i)*VSTRF + jb] = s2b*zB[1+i];
  }
  __syncthreads();

  // ---- Phase 3: layer 3 forward (PF3) ----
  gemv9f32(g_wsf + 32768, buf, o, kh, zA, zB);
  float z3a = zA[0] + b3[ja], z3b = zB[0] + b3[jb];
  float t3a[8], t3b[8];
#pragma unroll
  for (int i=0;i<8;++i){ t3a[i]=zA[1+i]; t3b[i]=zB[1+i]; }
  float s3a = sigf(z3a), s3b = sigf(z3b);
  __syncthreads();
  buf[ja] = spf(z3a); buf[jb] = spf(z3b);
#pragma unroll
  for (int i=0;i<8;++i){
    buf[(1+i)*VSTRF + ja] = s3a*zA[1+i];
    buf[(1+i)*VSTRF + jb] = s3b*zB[1+i];
  }
  __syncthreads();

  // ---- Phase 4+5: layer 4 forward (PF4) + head ----
  gemv9f32(g_wsf + 65536, buf, o, kh, zA, zB);
  {
    float z4a = zA[0] + b4[ja], z4b = zB[0] + b4[jb];
    float w5a = W5[ja], w5b = W5[jb];
    float sa = sigf(z4a), sb = sigf(z4b);
    float ca = w5a*sa*(1.0f-sa), cb = w5b*sb*(1.0f-sb);
    __syncthreads();
    buf[ja] = w5a*sa; buf[jb] = w5b*sb;                   // g_z4
#pragma unroll
    for (int i=0;i<8;++i){
      buf[(1+i)*VSTRF + ja] = ca*zA[1+i];                 // u_z4
      buf[(1+i)*VSTRF + jb] = cb*zB[1+i];
    }
  }
  __syncthreads();

  // ---- Phase 6: backward through W4^T (PB4) ----
  gemv9f32(g_wsf + 81920, buf, o, kh, zA, zB);
  {
    float da = s3a*(1.0f-s3a)*zA[0], db = s3b*(1.0f-s3b)*zB[0];
    __syncthreads();
    buf[ja] = zA[0]*s3a; buf[jb] = zB[0]*s3b;             // g_z3
#pragma unroll
    for (int i=0;i<8;++i){
      buf[(1+i)*VSTRF + ja] = fmaf(zA[1+i], s3a, da*t3a[i]);  // u_z3
      buf[(1+i)*VSTRF + jb] = fmaf(zB[1+i], s3b, db*t3b[i]);
    }
  }
  __syncthreads();

  // ---- Phase 7: backward through W3^T (PB3) ----
  gemv9f32(g_wsf + 49152, buf, o, kh, zA, zB);
  {
    float da = s2a*(1.0f-s2a)*zA[0], db = s2b*(1.0f-s2b)*zB[0];
    __syncthreads();
    buf[ja] = zA[0]*s2a; buf[jb] = zB[0]*s2b;             // g_z2
#pragma unroll
    for (int i=0;i<8;++i){
      buf[(1+i)*VSTRF + ja] = fmaf(zA[1+i], s2a, da*t2a[i]);  // u_z2
      buf[(1+i)*VSTRF + jb] = fmaf(zB[1+i], s2b, db*t2b[i]);
    }
  }
  __syncthreads();

  // ---- Phase 8: backward through W2^T (PB2); W1 tangent cols from phase-1 regs ----
  gemv9f32(g_wsf + 16384, buf, o, kh, zA, zB);
  {
    float da = s1a*(1.0f-s1a)*zA[0], db = s1b*(1.0f-s1b)*zB[0];
    __syncthreads();
    buf[ja] = zA[0]*s1a; buf[jb] = zB[0]*s1b;             // g_z1
#pragma unroll
    for (int i=0;i<8;++i){
      buf[(1+i)*VSTRF + ja] = fmaf(zA[1+i], s1a, da*w1af[i]); // u_z1
      buf[(1+i)*VSTRF + jb] = fmaf(zB[1+i], s1b, db*w1bf[i]);
    }
  }
  __syncthreads();

  // ---- Phase 9: H rows (8..15) + J via W1^T (PB1), pk-fma over k-pairs ----
  float hA, hB, hJ;
  {
    const int m = l & 15, d = l >> 4;
    const v4f* P1 = (const v4f*)(g_wsf + 98304);
    v2f aA={0.0f,0.0f}, aB={0.0f,0.0f}, aJ={0.0f,0.0f};
#pragma unroll 4
    for (int q=0; q<32; ++q){
      v4f wq = P1[q*DIM + m];             // W1[4q..4q+3][m]
      v2f wa=wq.xy, wb=wq.zw;
      v4f u0 = *((const v4f*)(buf + (1+d)*VSTRF + 4*q));
      v4f u1 = *((const v4f*)(buf + (5+d)*VSTRF + 4*q));
      v4f gg = *((const v4f*)(buf + 4*q));
      PKFMA(aA, wa, u0.xy); PKFMA(aA, wb, u0.zw);
      PKFMA(aB, wa, u1.xy); PKFMA(aB, wb, u1.zw);
      PKFMA(aJ, wa, gg.xy); PKFMA(aJ, wb, gg.zw);
    }
    hA = aA.x + aA.y;   // lane (m,d): H[8+d][m]
    hB = aB.x + aB.y;   // H[8+4+d][m]
    hJ = aJ.x + aJ.y;   // J[m]
  }

  // ---- Phase 10: y = pinv(B) @ (J[:8] - C qdot); all-f32 Jacobi solve ----
  {
    const int r = l >> 3, c = l & 7;
    float BvA = __shfl(hA, ((r&3)*16) + 8 + c);
    float BvB = __shfl(hB, ((r&3)*16) + 8 + c);
    float Bv  = (r < 4) ? BvA : BvB;              // B[r][c] = H[8+r][8+c]
    float CrA = __shfl(hA, ((r&3)*16) + c);
    float CrB = __shfl(hB, ((r&3)*16) + c);
    float Cr  = (r < 4) ? CrA : CrB;              // C[r][c] = H[8+r][c]
    float Jr  = __shfl(hJ, r);                    // J[r]
    float p0 = Cr * xs[8 + c];
    p0 += __shfl_xor(p0, 1); p0 += __shfl_xor(p0, 2); p0 += __shfl_xor(p0, 4);
    float rhs = Jr - p0;

    // symmetrize
    float Bt = __shfl(Bv, c*8 + r);
    float Am = 0.5f*(Bv + Bt);
    float Vm = (r == c) ? 1.0f : 0.0f;

    // Parallel-order (round-robin) Jacobi: 4 disjoint pairs/step, 7 steps/sweep, 4 sweeps.
    for (int sweep = 0; sweep < 4; ++sweep) {
#pragma unroll
      for (int rr = 0; rr < 7; ++rr) {
        int pc = (c == 7) ? rr : ((c == rr) ? 7 : (2*rr + 7 - c) % 7);
        int cp = min(c, pc), cq = max(c, pc);
        float App = __shfl(Am, cp*8+cp);
        float Aqq = __shfl(Am, cq*8+cq);
        float Apq = __shfl(Am, cp*8+cq);
        float tau = (Aqq - App) / (2.0f*Apq);
        float tt  = (tau >= 0.0f ? 1.0f : -1.0f) / (fabsf(tau) + sqrtf(1.0f + tau*tau));
        float cth = 1.0f / sqrtf(1.0f + tt*tt);
        float sth = tt * cth;
        if (fabsf(Apq) < 1e-30f) { cth = 1.0f; sth = 0.0f; }   // guard 0/0 -> NaN
        float cthr = __shfl(cth, r*8+r);
        float sthr = __shfl(sth, r*8+r);
        // column rotation: M = A*G
        float Arp = __shfl(Am, r*8+cp);
        float Arq = __shfl(Am, r*8+cq);
        float colv = (c == cp) ? (cth*Arp - sth*Arq) : (sth*Arp + cth*Arq);
        // row rotation: A = G^T*M
        int pr2 = (r == 7) ? rr : ((r == rr) ? 7 : (2*rr + 7 - r) % 7);
        int rp = min(r, pr2), rq = max(r, pr2);
        float Mpc = __shfl(colv, rp*8+c);
        float Mqc = __shfl(colv, rq*8+c);
        Am = (r == rp) ? (cthr*Mpc - sthr*Mqc) : (sthr*Mpc + cthr*Mqc);
        // V = V*G
        float Vrp = __shfl(Vm, r*8+cp);
        float Vrq = __shfl(Vm, r*8+cq);
        Vm = (c == cp) ? (cth*Vrp - sth*Vrq) : (sth*Vrp + cth*Vrq);
      }
    }

    // eigenvalue for this lane's column, and sigma_max = max |diag|
    float lam_c = __shfl(Am, c*8 + c);
    float adiag = (r == c) ? fabsf(Am) : 0.0f;
#pragma unroll
    for (int off = 32; off; off >>= 1) adiag = fmaxf(adiag, __shfl_xor(adiag, off));
    float cutoff = 9.5367431640625e-06f * adiag;   // 10*max(M,N)*eps_f32 * sigma_max

    // p_c = sum_r V[r][c]*rhs_r
    float pr = Vm * rhs;
    pr += __shfl_xor(pr, 8); pr += __shfl_xor(pr, 16); pr += __shfl_xor(pr, 32);
    float w = (fabsf(lam_c) > cutoff) ? (pr / lam_c) : 0.0f;
    // y_r = sum_c V[r][c]*w_c
    float yr = Vm * w;
    yr += __shfl_xor(yr, 1); yr += __shfl_xor(yr, 2); yr += __shfl_xor(yr, 4);
    if (c == 0) out[s*NPAR + r] = yr;
  }
}

extern "C" void kernel_launch(void* const* d_in, const int* in_sizes, int n_in,
                              void* d_out, int out_size, void* d_ws, size_t ws_size,
                              hipStream_t stream) {
  (void)in_sizes; (void)n_in; (void)out_size; (void)d_ws; (void)ws_size;
  const float* x  = (const float*)d_in[0];
  const float* W1 = (const float*)d_in[1];
  const float* b1 = (const float*)d_in[2];
  const float* W2 = (const float*)d_in[3];
  const float* b2 = (const float*)d_in[4];
  const float* W3 = (const float*)d_in[5];
  const float* b3 = (const float*)d_in[6];
  const float* W4 = (const float*)d_in[7];
  const float* b4 = (const float*)d_in[8];
  const float* W5 = (const float*)d_in[9];
  float* out = (float*)d_out;

  // (6*128*128 + 128*16) / 4 = 25088 float4 writes, 98 blocks * 256 threads
  pack_weights<<<98, 256, 0, stream>>>(W1, W2, W3, W4);
  lnn_main<<<BATCH, 64, 0, stream>>>(x, W1, b1, b2, b3, b4, W5, out);
}